// Round 2
// baseline (5682.884 us; speedup 1.0000x reference)
//
#include <hip/hip_runtime.h>

typedef __attribute__((ext_vector_type(8))) short short8;
typedef __attribute__((ext_vector_type(4))) float floatx4;

#define DIN  512
#define HSZ  1024
#define G4   4096
#define KTOT 1536
#define BQ   256
#define TT   256
#define ROWS 128
#define WSTRIDE 3072  // bytes per W row in LDS (1536 bf16)

#define MFMA __builtin_amdgcn_mfma_f32_16x16x32_bf16

__device__ __forceinline__ unsigned short f2bf(float f){
  unsigned int u = __float_as_uint(f);
  u += 0x7fffu + ((u >> 16) & 1u);
  return (unsigned short)(u >> 16);
}
__device__ __forceinline__ unsigned int pack2(float a, float b){
  return (unsigned int)f2bf(a) | ((unsigned int)f2bf(b) << 16);
}

// ---------------- prep kernels ----------------
__global__ void prep_wcat(const float* __restrict__ wx, const float* __restrict__ wh,
                          const float* __restrict__ bx, const float* __restrict__ bh,
                          unsigned short* __restrict__ Wcat, float* __restrict__ bias){
  int gid = blockIdx.x * blockDim.x + threadIdx.x;
  int idx = gid * 8;
  int g = idx / KTOT;
  int k = idx - g * KTOT;
  const float* src = (k < DIN) ? (wx + (size_t)g * DIN + k)
                               : (wh + (size_t)g * HSZ + (k - DIN));
  float4 f0 = *(const float4*)(src);
  float4 f1 = *(const float4*)(src + 4);
  uint4 v = make_uint4(pack2(f0.x,f0.y), pack2(f0.z,f0.w), pack2(f1.x,f1.y), pack2(f1.z,f1.w));
  *(uint4*)(Wcat + (size_t)g * KTOT + k) = v;
  if (gid < G4) bias[gid] = bx[gid] + bh[gid];
}

__global__ void prep_wfc(const float* __restrict__ wfc, unsigned short* __restrict__ Wfcb){
  int gid = blockIdx.x * blockDim.x + threadIdx.x;
  int idx = gid * 8;
  int n = idx >> 10;
  int k = idx & 1023;
  uint4 v;
  if (n < 1000){
    const float* src = wfc + (size_t)n * 1024 + k;
    float4 f0 = *(const float4*)(src);
    float4 f1 = *(const float4*)(src + 4);
    v = make_uint4(pack2(f0.x,f0.y), pack2(f0.z,f0.w), pack2(f1.x,f1.y), pack2(f1.z,f1.w));
  } else {
    v = make_uint4(0u, 0u, 0u, 0u);
  }
  *(uint4*)(Wfcb + idx) = v;
}

// x[b][t][d] fp32 -> xbf[t][b][d] bf16
__global__ void prep_x(const float* __restrict__ x, unsigned short* __restrict__ xbf){
  int gid = blockIdx.x * 256 + threadIdx.x;
  int d8 = gid & 63;
  int b  = (gid >> 6) & 255;
  int t  = gid >> 14;
  const float* src = x + (((size_t)b * TT) + t) * DIN + d8 * 8;
  float4 f0 = *(const float4*)(src);
  float4 f1 = *(const float4*)(src + 4);
  uint4 v = make_uint4(pack2(f0.x,f0.y), pack2(f0.z,f0.w), pack2(f1.x,f1.y), pack2(f1.z,f1.w));
  *(uint4*)(xbf + (((size_t)t * BQ) + b) * DIN + d8 * 8) = v;
}

__global__ void init_misc(unsigned int* __restrict__ h0w, unsigned int* __restrict__ barw, int nbar){
  int gid = blockIdx.x * 256 + threadIdx.x;
  if (gid < 131072) h0w[gid] = 0u;   // h0: 256*1024 bf16 = 131072 u32
  if (gid < nbar)   barw[gid] = 0u;
}

// ---------------- persistent LSTM ----------------
// grid = 256 blocks (1/CU). block bx: hb = bx>>1 (8 hidden units), b0 = (bx&1)*128.
// W slice (32 gate-cols x 1536) resident in LDS for all 256 steps.
__global__ __launch_bounds__(256, 1)
void lstm_persist(const unsigned short* __restrict__ xbf,
                  const unsigned short* __restrict__ Wcat,
                  const float* __restrict__ bias,
                  unsigned short* __restrict__ h0,
                  unsigned short* __restrict__ h1,
                  unsigned int* __restrict__ leaf,
                  unsigned int* __restrict__ root){
  extern __shared__ char smem[];
  char*  Bs  = smem;                       // 32 * 3072 = 98304 B
  float* Bls = (float*)(smem + 98304);     // 32 floats

  const int tid  = threadIdx.x;
  const int bx   = blockIdx.x;
  const int hb   = bx >> 1;
  const int b0   = (bx & 1) * ROWS;
  const int lane = tid & 63;
  const int wave = tid >> 6;

  // ---- one-time: W slice -> LDS (XOR swizzled), bias -> LDS ----
  {
    int c = tid >> 3;           // 0..31 (gate-col within slice)
    int chunk = tid & 7;        // 8 threads/row, 384B each
    int grow = (c >> 3) * HSZ + hb * 8 + (c & 7);
    const char* src = (const char*)(Wcat + (size_t)grow * KTOT);
    char* dstrow = Bs + c * WSTRIDE;
    int xr = (c & 7) << 4;
    #pragma unroll
    for (int j = 0; j < 24; ++j){
      int k2 = chunk * 384 + j * 16;
      *(uint4*)(dstrow + (k2 ^ xr)) = *(const uint4*)(src + k2);
    }
    if (tid < 32)
      Bls[tid] = bias[(size_t)(tid >> 3) * HSZ + hb * 8 + (tid & 7)];
  }
  __syncthreads();

  const int rowbase = b0 + wave * 32 + (lane & 15);
  const int kgrp = (lane >> 4) * 8;
  const int colA = (lane & 15);
  const int colB = 16 + (lane & 15);
  const char* bptrA = Bs + colA * WSTRIDE; const int xrA = (colA & 7) << 4;
  const char* bptrB = Bs + colB * WSTRIDE; const int xrB = (colB & 7) << 4;

  const float bi0 = Bls[lane & 15];
  const float bi1 = Bls[16 + (lane & 15)];

  float cst[2][4];
  #pragma unroll
  for (int rf = 0; rf < 2; ++rf)
    #pragma unroll
    for (int r = 0; r < 4; ++r) cst[rf][r] = 0.f;

  auto hload8 = [&](const unsigned short* base, int kh) -> short8 {
    const unsigned long long* p = (const unsigned long long*)(base + kh);
    unsigned long long u0 = __hip_atomic_load(p,     __ATOMIC_RELAXED, __HIP_MEMORY_SCOPE_AGENT);
    unsigned long long u1 = __hip_atomic_load(p + 1, __ATOMIC_RELAXED, __HIP_MEMORY_SCOPE_AGENT);
    union { unsigned long long q[2]; short8 s; } uu;
    uu.q[0] = u0; uu.q[1] = u1;
    return uu.s;
  };

  for (int t = 0; t < TT; ++t){
    const unsigned short* hin  = (t & 1) ? h1 : h0;
    unsigned short*       hout = (t & 1) ? h0 : h1;

    floatx4 acc[4][2][2];
    #pragma unroll
    for (int s = 0; s < 4; ++s)
      #pragma unroll
      for (int rf = 0; rf < 2; ++rf)
        #pragma unroll
        for (int cf = 0; cf < 2; ++cf)
          acc[s][rf][cf] = (floatx4){0.f, 0.f, 0.f, 0.f};

    // ===== x-part (ks 0..15): independent of h[t] — runs before barrier wait =====
    const unsigned short* xrow0 = xbf + ((size_t)t * BQ + rowbase) * DIN;
    const unsigned short* xrow1 = xrow0 + (size_t)16 * DIN;
    {
      short8 ax[4][2]; short8 bxv[4][2];
      #pragma unroll
      for (int p = 0; p < 4; ++p){
        int k = p * 32 + kgrp;
        ax[p][0] = *(const short8*)(xrow0 + k);
        ax[p][1] = *(const short8*)(xrow1 + k);
        bxv[p][0] = *(const short8*)(bptrA + ((2 * k) ^ xrA));
        bxv[p][1] = *(const short8*)(bptrB + ((2 * k) ^ xrB));
      }
      #pragma unroll
      for (int ks = 0; ks < 16; ++ks){
        const int sl = ks & 3;
        acc[sl][0][0] = MFMA(ax[sl][0], bxv[sl][0], acc[sl][0][0], 0, 0, 0);
        acc[sl][0][1] = MFMA(ax[sl][0], bxv[sl][1], acc[sl][0][1], 0, 0, 0);
        acc[sl][1][0] = MFMA(ax[sl][1], bxv[sl][0], acc[sl][1][0], 0, 0, 0);
        acc[sl][1][1] = MFMA(ax[sl][1], bxv[sl][1], acc[sl][1][1], 0, 0, 0);
        if (ks < 12){
          int k = (ks + 4) * 32 + kgrp;
          ax[sl][0] = *(const short8*)(xrow0 + k);
          ax[sl][1] = *(const short8*)(xrow1 + k);
          bxv[sl][0] = *(const short8*)(bptrA + ((2 * k) ^ xrA));
          bxv[sl][1] = *(const short8*)(bptrB + ((2 * k) ^ xrB));
        }
      }
    }

    // ===== wait: h[t] ready (producers arrived at bar[t]) =====
    if (t > 0){
      if (tid == 0){
        while (__hip_atomic_load(&root[t * 16], __ATOMIC_RELAXED, __HIP_MEMORY_SCOPE_AGENT) < 16u)
          __builtin_amdgcn_s_sleep(1);
      }
      __syncthreads();
    }

    // ===== h-part (ks 16..47), 8-deep prefetch, sc1 loads bypass L1/L2 =====
    const unsigned short* hrow0 = hin + (size_t)rowbase * HSZ;
    const unsigned short* hrow1 = hrow0 + (size_t)16 * HSZ;
    {
      short8 ah[8][2]; short8 bhv[8][2];
      #pragma unroll
      for (int p = 0; p < 8; ++p){
        int kh = p * 32 + kgrp;
        ah[p][0] = hload8(hrow0, kh);
        ah[p][1] = hload8(hrow1, kh);
        int kb = 1024 + 2 * kh;
        bhv[p][0] = *(const short8*)(bptrA + (kb ^ xrA));
        bhv[p][1] = *(const short8*)(bptrB + (kb ^ xrB));
      }
      #pragma unroll
      for (int ks = 0; ks < 32; ++ks){
        const int sl = ks & 7;
        const int as = ks & 3;
        acc[as][0][0] = MFMA(ah[sl][0], bhv[sl][0], acc[as][0][0], 0, 0, 0);
        acc[as][0][1] = MFMA(ah[sl][0], bhv[sl][1], acc[as][0][1], 0, 0, 0);
        acc[as][1][0] = MFMA(ah[sl][1], bhv[sl][0], acc[as][1][0], 0, 0, 0);
        acc[as][1][1] = MFMA(ah[sl][1], bhv[sl][1], acc[as][1][1], 0, 0, 0);
        if (ks < 24){
          int kh = (ks + 8) * 32 + kgrp;
          ah[sl][0] = hload8(hrow0, kh);
          ah[sl][1] = hload8(hrow1, kh);
          int kb = 1024 + 2 * kh;
          bhv[sl][0] = *(const short8*)(bptrA + (kb ^ xrA));
          bhv[sl][1] = *(const short8*)(bptrB + (kb ^ xrB));
        }
      }
    }

    floatx4 g[2][2];
    #pragma unroll
    for (int rf = 0; rf < 2; ++rf)
      #pragma unroll
      for (int cf = 0; cf < 2; ++cf)
        g[rf][cf] = acc[0][rf][cf] + acc[1][rf][cf] + acc[2][rf][cf] + acc[3][rf][cf];

    // ===== elementwise: gates -> c (regs), h (sc1 u32 stores) =====
    #pragma unroll
    for (int rf = 0; rf < 2; ++rf){
      #pragma unroll
      for (int r = 0; r < 4; ++r){
        float v0 = g[rf][0][r] + bi0;       // col<16: gate i (lane&8==0) / f
        float v1 = g[rf][1][r] + bi1;       // col 16..31: gate g / o
        float p0 = __shfl_xor(v0, 8, 64);
        float p1 = __shfl_xor(v1, 8, 64);
        float iv = 1.f / (1.f + __expf(-v0));
        float fv = 1.f / (1.f + __expf(-p0));
        float e2 = __expf(-2.f * fmaxf(fminf(v1, 30.f), -30.f));
        float gv = (1.f - e2) / (1.f + e2);
        float ov = 1.f / (1.f + __expf(-p1));
        float cn = cst[rf][r] * fv + iv * gv;
        cst[rf][r] = cn;
        float e2c = __expf(-2.f * fmaxf(fminf(cn, 30.f), -30.f));
        float hv = ov * (1.f - e2c) / (1.f + e2c);
        unsigned int hb16 = f2bf(hv);
        unsigned int pr = (unsigned int)__shfl_xor((int)hb16, 1, 64);
        if ((lane & 9) == 0){
          int row = b0 + wave * 32 + rf * 16 + (lane >> 4) * 4 + r;
          int u = hb * 8 + (lane & 7);
          __hip_atomic_store((unsigned int*)(hout + (size_t)row * HSZ + u),
                             hb16 | (pr << 16), __ATOMIC_RELAXED, __HIP_MEMORY_SCOPE_AGENT);
        }
      }
    }

    // ===== arrive at bar[t+1]: h[t+1] published =====
    __syncthreads();   // drains all waves' h-stores (vmcnt 0)
    if (tid == 0){
      unsigned int old = __hip_atomic_fetch_add(&leaf[((t + 1) * 16 + (bx >> 4)) * 16], 1u,
                                                __ATOMIC_RELAXED, __HIP_MEMORY_SCOPE_AGENT);
      if (old == 15u)
        __hip_atomic_fetch_add(&root[(t + 1) * 16], 1u,
                               __ATOMIC_RELAXED, __HIP_MEMORY_SCOPE_AGENT);
    }
  }
}

// ---------------- final FC: out[256][1000] = h @ Wfc^T + b ----------------
__global__ __launch_bounds__(256, 1)
void fc_kernel(const unsigned short* __restrict__ h, const unsigned short* __restrict__ wfc,
               const float* __restrict__ bfc, float* __restrict__ out){
  int bx = blockIdx.x, tid = threadIdx.x;
  int wave = tid >> 6, lane = tid & 63;
  int row0 = (bx >> 4) * 64 + wave * 16;
  int col0 = (bx & 15) * 64;
  int lr = lane & 15, lk = (lane >> 4) * 8;
  floatx4 acc[4] = {{0.f,0.f,0.f,0.f},{0.f,0.f,0.f,0.f},{0.f,0.f,0.f,0.f},{0.f,0.f,0.f,0.f}};
  #pragma unroll 4
  for (int ks = 0; ks < 32; ++ks){
    int k = ks * 32 + lk;
    short8 a = *(const short8*)(h + (size_t)(row0 + lr) * 1024 + k);
    #pragma unroll
    for (int fj = 0; fj < 4; ++fj){
      short8 b = *(const short8*)(wfc + (size_t)(col0 + fj * 16 + lr) * 1024 + k);
      acc[fj] = MFMA(a, b, acc[fj], 0, 0, 0);
    }
  }
  #pragma unroll
  for (int fj = 0; fj < 4; ++fj){
    int col = col0 + fj * 16 + lr;
    if (col < 1000){
      #pragma unroll
      for (int r = 0; r < 4; ++r){
        int row = row0 + (lane >> 4) * 4 + r;
        out[(size_t)row * 1000 + col] = acc[fj][r] + bfc[col];
      }
    }
  }
}

// ---------------- launch ----------------
extern "C" void kernel_launch(void* const* d_in, const int* in_sizes, int n_in,
                              void* d_out, int out_size, void* d_ws, size_t ws_size,
                              hipStream_t stream){
  const float* x    = (const float*)d_in[0];
  const float* wx2h = (const float*)d_in[1];
  const float* bx2h = (const float*)d_in[2];
  const float* wh2h = (const float*)d_in[3];
  const float* bh2h = (const float*)d_in[4];
  const float* wfc  = (const float*)d_in[5];
  const float* bfc  = (const float*)d_in[6];
  float* out = (float*)d_out;
  char* ws = (char*)d_ws;

  // ws layout (bytes)
  unsigned short* Wcat = (unsigned short*)(ws + 0);            // 12,582,912
  unsigned short* Wfcb = (unsigned short*)(ws + 12582912);     //  2,097,152
  float*          bias = (float*)         (ws + 14680064);     //     16,384
  unsigned short* h0   = (unsigned short*)(ws + 14696448);     //    524,288
  unsigned short* h1   = (unsigned short*)(ws + 15220736);     //    524,288
  unsigned short* xbf  = (unsigned short*)(ws + 15745024);     // 67,108,864
  unsigned int*   leaf = (unsigned int*)  (ws + 82853888);     //    263,168
  unsigned int*   root = (unsigned int*)  (ws + 83117056);     //     16,448
  // total ~83.1 MB

  (void)hipFuncSetAttribute((const void*)lstm_persist,
                            hipFuncAttributeMaxDynamicSharedMemorySize, 98432);

  hipLaunchKernelGGL(prep_wcat, dim3(3072), dim3(256), 0, stream, wx2h, wh2h, bx2h, bh2h, Wcat, bias);
  hipLaunchKernelGGL(prep_wfc,  dim3(512),  dim3(256), 0, stream, wfc, Wfcb);
  hipLaunchKernelGGL(prep_x,    dim3(16384),dim3(256), 0, stream, x, xbf);
  hipLaunchKernelGGL(init_misc, dim3(512),  dim3(256), 0, stream,
                     (unsigned int*)h0, leaf, (int)((263168 + 16448) / 4));

  hipLaunchKernelGGL(lstm_persist, dim3(256), dim3(256), 98432, stream,
                     xbf, Wcat, bias, h0, h1, leaf, root);

  // t=255 writes h0; FC consumes it
  hipLaunchKernelGGL(fc_kernel, dim3(64), dim3(256), 0, stream, h0, Wfcb, bfc, out);
}

// Round 3
// 3181.669 us; speedup vs baseline: 1.7861x; 1.7861x over previous
//
#include <hip/hip_runtime.h>

typedef __attribute__((ext_vector_type(8))) short short8;
typedef __attribute__((ext_vector_type(4))) float floatx4;

#define DIN  512
#define HSZ  1024
#define G4   4096
#define KTOT 1536
#define BQ   256
#define TT   256

#define MFMA __builtin_amdgcn_mfma_f32_16x16x32_bf16

__device__ __forceinline__ unsigned short f2bf(float f){
  unsigned int u = __float_as_uint(f);
  u += 0x7fffu + ((u >> 16) & 1u);
  return (unsigned short)(u >> 16);
}
__device__ __forceinline__ unsigned int pack2(float a, float b){
  return (unsigned int)f2bf(a) | ((unsigned int)f2bf(b) << 16);
}

// ---------------- prep kernels ----------------
__global__ void prep_wcat(const float* __restrict__ wx, const float* __restrict__ wh,
                          const float* __restrict__ bx, const float* __restrict__ bh,
                          unsigned short* __restrict__ Wcat, float* __restrict__ bias){
  int gid = blockIdx.x * blockDim.x + threadIdx.x;
  int idx = gid * 8;
  int g = idx / KTOT;
  int k = idx - g * KTOT;
  const float* src = (k < DIN) ? (wx + (size_t)g * DIN + k)
                               : (wh + (size_t)g * HSZ + (k - DIN));
  float4 f0 = *(const float4*)(src);
  float4 f1 = *(const float4*)(src + 4);
  uint4 v = make_uint4(pack2(f0.x,f0.y), pack2(f0.z,f0.w), pack2(f1.x,f1.y), pack2(f1.z,f1.w));
  *(uint4*)(Wcat + (size_t)g * KTOT + k) = v;
  if (gid < G4) bias[gid] = bx[gid] + bh[gid];
}

__global__ void prep_wfc(const float* __restrict__ wfc, unsigned short* __restrict__ Wfcb){
  int gid = blockIdx.x * blockDim.x + threadIdx.x;
  int idx = gid * 8;
  int n = idx >> 10;
  int k = idx & 1023;
  uint4 v;
  if (n < 1000){
    const float* src = wfc + (size_t)n * 1024 + k;
    float4 f0 = *(const float4*)(src);
    float4 f1 = *(const float4*)(src + 4);
    v = make_uint4(pack2(f0.x,f0.y), pack2(f0.z,f0.w), pack2(f1.x,f1.y), pack2(f1.z,f1.w));
  } else {
    v = make_uint4(0u, 0u, 0u, 0u);
  }
  *(uint4*)(Wfcb + idx) = v;
}

// x[b][t][d] fp32 -> xbf[t][b][d] bf16
__global__ void prep_x(const float* __restrict__ x, unsigned short* __restrict__ xbf){
  int gid = blockIdx.x * 256 + threadIdx.x;
  int d8 = gid & 63;
  int b  = (gid >> 6) & 255;
  int t  = gid >> 14;
  const float* src = x + (((size_t)b * TT) + t) * DIN + d8 * 8;
  float4 f0 = *(const float4*)(src);
  float4 f1 = *(const float4*)(src + 4);
  uint4 v = make_uint4(pack2(f0.x,f0.y), pack2(f0.z,f0.w), pack2(f1.x,f1.y), pack2(f1.z,f1.w));
  *(uint4*)(xbf + (((size_t)t * BQ) + b) * DIN + d8 * 8) = v;
}

__global__ void init_misc(unsigned int* __restrict__ h0w, unsigned int* __restrict__ flags, int nflags){
  int gid = blockIdx.x * 256 + threadIdx.x;
  if (gid < 131072) h0w[gid] = 0u;   // hseq[0]: 256*1024 bf16
  if (gid < nflags) flags[gid] = 0u;
}

// ---------------- persistent LSTM ----------------
// 256 blocks x 512 threads. bg = bx>>7 (128-row batch half), hb = bx&127 (8 units).
// W slice (32 gate-cols x 1536) resident in LDS. h exchanged via per-step buffers:
// producers store device-scope (sc1 -> L3); consumers use PLAIN loads at fresh
// addresses (L2-cacheable, first-touch per step => never stale).
__global__ __launch_bounds__(512, 2)
void lstm_persist(const unsigned short* __restrict__ xbf,
                  const unsigned short* __restrict__ Wcat,
                  const float* __restrict__ bias,
                  unsigned short* __restrict__ hseq,      // [257][256][1024] bf16
                  unsigned int* __restrict__ leafcnt,     // [257][2][8] x16
                  unsigned int* __restrict__ rootcnt,     // [257][2] x16
                  unsigned int* __restrict__ done){       // [257][2][16] x16
  extern __shared__ char smem[];
  char*  Ws  = smem;                           // 32 * 3072 = 98304
  float* Gt  = (float*)(smem + 98304);         // 128 * 33 * 4 = 16896
  float* Bls = (float*)(smem + 98304 + 16896); // 32 floats

  const int tid  = threadIdx.x;
  const int bx   = blockIdx.x;
  const int bg   = bx >> 7;
  const int hb   = bx & 127;
  const int b0   = bg << 7;        // 128-row batch half
  const int u0   = hb << 3;        // 8 hidden units
  const int lane = tid & 63;
  const int rg   = tid >> 6;       // wave = row-group (16 rows each)

  // ---- one-time: W slice -> LDS (XOR swizzled), bias -> LDS ----
  {
    int c  = tid >> 4;             // 0..31: col = gate*8 + unit
    int ch = tid & 15;             // 16 threads/row, 192 B each
    int g  = c >> 3, j = c & 7;
    const char* src = (const char*)(Wcat + (size_t)(g * HSZ + u0 + j) * KTOT);
    char* dst = Ws + c * 3072;
    int xr = j << 4;
    #pragma unroll
    for (int q = 0; q < 12; ++q){
      int k2 = ch * 192 + q * 16;
      *(uint4*)(dst + (k2 ^ xr)) = *(const uint4*)(src + k2);
    }
    if (tid < 32) Bls[tid] = bias[(size_t)(tid >> 3) * HSZ + u0 + (tid & 7)];
  }
  __syncthreads();

  const int arow = lane & 15;          // local row in wave's 16
  const int kq8  = (lane >> 4) * 8;    // k element offset
  const int cc0  = lane & 15;          // B col for cf=0
  const int cc1  = 16 + (lane & 15);   // B col for cf=1
  const char* bp0 = Ws + cc0 * 3072; const int xr0 = (cc0 & 7) << 4;
  const char* bp1 = Ws + cc1 * 3072; const int xr1 = (cc1 & 7) << 4;

  // elementwise mapping (fixed per thread across steps; c-state in regs)
  const int erow = tid >> 2;           // 0..127
  const int eup  = (tid & 3) * 2;      // unit pair 0,2,4,6
  float cst0 = 0.f, cst1 = 0.f;

  const size_t growbase = (size_t)(b0 + rg * 16 + arow);

  for (int t = 0; t < TT; ++t){
    const unsigned short* hin  = hseq + (size_t)t * (BQ * HSZ);
    unsigned short*       hout = hseq + (size_t)(t + 1) * (BQ * HSZ);

    floatx4 acc[4][2];
    #pragma unroll
    for (int s = 0; s < 4; ++s){
      acc[s][0] = (floatx4){0.f,0.f,0.f,0.f};
      acc[s][1] = (floatx4){0.f,0.f,0.f,0.f};
    }

    // ===== x-part (K 0..511): independent of h[t], runs before the wait =====
    {
      const unsigned short* xrow = xbf + ((size_t)t * BQ + growbase) * DIN + kq8;
      short8 av[4]; short8 bv[4][2];
      #pragma unroll
      for (int p = 0; p < 4; ++p){
        int k = p * 32;
        av[p]    = *(const short8*)(xrow + k);
        bv[p][0] = *(const short8*)(bp0 + ((2 * (k + kq8)) ^ xr0));
        bv[p][1] = *(const short8*)(bp1 + ((2 * (k + kq8)) ^ xr1));
      }
      #pragma unroll
      for (int ks = 0; ks < 16; ++ks){
        int sl = ks & 3;
        acc[sl][0] = MFMA(av[sl], bv[sl][0], acc[sl][0], 0, 0, 0);
        acc[sl][1] = MFMA(av[sl], bv[sl][1], acc[sl][1], 0, 0, 0);
        if (ks < 12){
          int k = (ks + 4) * 32;
          av[sl]    = *(const short8*)(xrow + k);
          bv[sl][0] = *(const short8*)(bp0 + ((2 * (k + kq8)) ^ xr0));
          bv[sl][1] = *(const short8*)(bp1 + ((2 * (k + kq8)) ^ xr1));
        }
      }
    }

    // ===== wait: hseq[t] published (only own bg's 128 producers matter) =====
    if (t > 0){
      if (tid == 0){
        const unsigned int* dp = &done[(((size_t)t * 2 + bg) * 16 + (hb & 15)) * 16];
        while (__hip_atomic_load(dp, __ATOMIC_RELAXED, __HIP_MEMORY_SCOPE_AGENT) == 0u)
          __builtin_amdgcn_s_sleep(2);
      }
      __syncthreads();
      asm volatile("" ::: "memory");
    }

    // ===== h-part (K 512..1535): PLAIN loads, L2-served =====
    {
      const unsigned short* hrow = hin + growbase * HSZ + kq8;
      short8 ah[8]; short8 bh[8][2];
      #pragma unroll
      for (int p = 0; p < 8; ++p){
        int k = p * 32;
        ah[p] = *(const short8*)(hrow + k);
        int kb = 1024 + 2 * (k + kq8);
        bh[p][0] = *(const short8*)(bp0 + (kb ^ xr0));
        bh[p][1] = *(const short8*)(bp1 + (kb ^ xr1));
      }
      #pragma unroll
      for (int ks = 0; ks < 32; ++ks){
        int sl = ks & 7, as = ks & 3;
        acc[as][0] = MFMA(ah[sl], bh[sl][0], acc[as][0], 0, 0, 0);
        acc[as][1] = MFMA(ah[sl], bh[sl][1], acc[as][1], 0, 0, 0);
        if (ks < 24){
          int k = (ks + 8) * 32;
          ah[sl] = *(const short8*)(hrow + k);
          int kb = 1024 + 2 * (k + kq8);
          bh[sl][0] = *(const short8*)(bp0 + (kb ^ xr0));
          bh[sl][1] = *(const short8*)(bp1 + (kb ^ xr1));
        }
      }
    }

    floatx4 g0 = acc[0][0] + acc[1][0] + acc[2][0] + acc[3][0];
    floatx4 g1 = acc[0][1] + acc[1][1] + acc[2][1] + acc[3][1];

    // gates -> LDS
    {
      int r0 = rg * 16 + (lane >> 4) * 4;
      #pragma unroll
      for (int r = 0; r < 4; ++r){
        Gt[(r0 + r) * 33 + cc0] = g0[r];
        Gt[(r0 + r) * 33 + cc1] = g1[r];
      }
    }
    __syncthreads();

    // elementwise: 2 units per thread; c in regs; h pair-packed sc1 store
    {
      float cn0, cn1;
      {
        float gi = Gt[erow * 33 +      eup] + Bls[     eup];
        float gf = Gt[erow * 33 +  8 + eup] + Bls[ 8 + eup];
        float gg = Gt[erow * 33 + 16 + eup] + Bls[16 + eup];
        float go = Gt[erow * 33 + 24 + eup] + Bls[24 + eup];
        float iv = 1.f / (1.f + __expf(-gi));
        float fv = 1.f / (1.f + __expf(-gf));
        float e2 = __expf(-2.f * fmaxf(fminf(gg, 30.f), -30.f));
        float gv = (1.f - e2) / (1.f + e2);
        float ov = 1.f / (1.f + __expf(-go));
        cn0 = cst0 * fv + iv * gv;
        cst0 = cn0;
      }
      {
        float gi = Gt[erow * 33 +      eup + 1] + Bls[     eup + 1];
        float gf = Gt[erow * 33 +  8 + eup + 1] + Bls[ 8 + eup + 1];
        float gg = Gt[erow * 33 + 16 + eup + 1] + Bls[16 + eup + 1];
        float go = Gt[erow * 33 + 24 + eup + 1] + Bls[24 + eup + 1];
        float iv = 1.f / (1.f + __expf(-gi));
        float fv = 1.f / (1.f + __expf(-gf));
        float e2 = __expf(-2.f * fmaxf(fminf(gg, 30.f), -30.f));
        float gv = (1.f - e2) / (1.f + e2);
        float ov = 1.f / (1.f + __expf(-go));
        cn1 = cst1 * fv + iv * gv;
        cst1 = cn1;
        float e2c0 = __expf(-2.f * fmaxf(fminf(cn0, 30.f), -30.f));
        float h0v  = (1.f - e2c0) / (1.f + e2c0);
        float e2c1 = __expf(-2.f * fmaxf(fminf(cn1, 30.f), -30.f));
        float h1v  = (1.f - e2c1) / (1.f + e2c1);
        // recompute ov for unit0:
        float go0 = Gt[erow * 33 + 24 + eup] + Bls[24 + eup];
        float ov0 = 1.f / (1.f + __expf(-go0));
        unsigned int packed = pack2(ov0 * h0v, ov * h1v);
        __hip_atomic_store((unsigned int*)(hout + (size_t)(b0 + erow) * HSZ + u0 + eup),
                           packed, __ATOMIC_RELAXED, __HIP_MEMORY_SCOPE_AGENT);
      }
    }
    __syncthreads();  // drains h-stores (vmcnt 0) in every wave before arrive

    // ===== arrive: hseq[t+1] published =====
    if (tid == 0){
      unsigned int old = __hip_atomic_fetch_add(
          &leafcnt[(((size_t)(t + 1) * 2 + bg) * 8 + (hb >> 4)) * 16], 1u,
          __ATOMIC_RELAXED, __HIP_MEMORY_SCOPE_AGENT);
      if (old == 15u){
        unsigned int old2 = __hip_atomic_fetch_add(
            &rootcnt[((size_t)(t + 1) * 2 + bg) * 16], 1u,
            __ATOMIC_RELAXED, __HIP_MEMORY_SCOPE_AGENT);
        if (old2 == 7u){
          #pragma unroll
          for (int cpy = 0; cpy < 16; ++cpy)
            __hip_atomic_store(&done[(((size_t)(t + 1) * 2 + bg) * 16 + cpy) * 16], 1u,
                               __ATOMIC_RELAXED, __HIP_MEMORY_SCOPE_AGENT);
        }
      }
    }
  }
}

// ---------------- final FC: out[256][1000] = h @ Wfc^T + b ----------------
__global__ __launch_bounds__(256, 1)
void fc_kernel(const unsigned short* __restrict__ h, const unsigned short* __restrict__ wfc,
               const float* __restrict__ bfc, float* __restrict__ out){
  int bx = blockIdx.x, tid = threadIdx.x;
  int wave = tid >> 6, lane = tid & 63;
  int row0 = (bx >> 4) * 64 + wave * 16;
  int col0 = (bx & 15) * 64;
  int lr = lane & 15, lk = (lane >> 4) * 8;
  floatx4 acc[4] = {{0.f,0.f,0.f,0.f},{0.f,0.f,0.f,0.f},{0.f,0.f,0.f,0.f},{0.f,0.f,0.f,0.f}};
  #pragma unroll 4
  for (int ks = 0; ks < 32; ++ks){
    int k = ks * 32 + lk;
    short8 a = *(const short8*)(h + (size_t)(row0 + lr) * 1024 + k);
    #pragma unroll
    for (int fj = 0; fj < 4; ++fj){
      short8 b = *(const short8*)(wfc + (size_t)(col0 + fj * 16 + lr) * 1024 + k);
      acc[fj] = MFMA(a, b, acc[fj], 0, 0, 0);
    }
  }
  #pragma unroll
  for (int fj = 0; fj < 4; ++fj){
    int col = col0 + fj * 16 + lr;
    if (col < 1000){
      #pragma unroll
      for (int r = 0; r < 4; ++r){
        int row = row0 + (lane >> 4) * 4 + r;
        out[(size_t)row * 1000 + col] = acc[fj][r] + bfc[col];
      }
    }
  }
}

// ---------------- launch ----------------
extern "C" void kernel_launch(void* const* d_in, const int* in_sizes, int n_in,
                              void* d_out, int out_size, void* d_ws, size_t ws_size,
                              hipStream_t stream){
  const float* x    = (const float*)d_in[0];
  const float* wx2h = (const float*)d_in[1];
  const float* bx2h = (const float*)d_in[2];
  const float* wh2h = (const float*)d_in[3];
  const float* bh2h = (const float*)d_in[4];
  const float* wfc  = (const float*)d_in[5];
  const float* bfc  = (const float*)d_in[6];
  float* out = (float*)d_out;
  char* ws = (char*)d_ws;

  // ws layout (bytes)
  unsigned short* Wcat = (unsigned short*)(ws + 0);              //  12,582,912
  unsigned short* Wfcb = (unsigned short*)(ws + 12582912);       //   2,097,152
  float*          bias = (float*)         (ws + 14680064);       //      16,384
  unsigned short* xbf  = (unsigned short*)(ws + 14696448);       //  67,108,864
  unsigned short* hseq = (unsigned short*)(ws + 81805312);       // 134,742,016 (257 x 512KB)
  unsigned int*   leaf = (unsigned int*)  (ws + 216547328);      //     263,168
  unsigned int*   root = (unsigned int*)  (ws + 216810496);      //      32,896
  unsigned int*   done = (unsigned int*)  (ws + 216843392);      //   1,052,672
  // total ~217.9 MB

  (void)hipFuncSetAttribute((const void*)lstm_persist,
                            hipFuncAttributeMaxDynamicSharedMemorySize, 115456);

  hipLaunchKernelGGL(prep_wcat, dim3(3072), dim3(256), 0, stream, wx2h, wh2h, bx2h, bh2h, Wcat, bias);
  hipLaunchKernelGGL(prep_wfc,  dim3(512),  dim3(256), 0, stream, wfc, Wfcb);
  hipLaunchKernelGGL(prep_x,    dim3(16384),dim3(256), 0, stream, x, xbf);
  hipLaunchKernelGGL(init_misc, dim3(1318), dim3(256), 0, stream,
                     (unsigned int*)hseq, leaf, (int)((263168 + 32896 + 1052672) / 4));

  hipLaunchKernelGGL(lstm_persist, dim3(256), dim3(512), 115456, stream,
                     xbf, Wcat, bias, hseq, leaf, root, done);

  // final h = hseq[256]
  hipLaunchKernelGGL(fc_kernel, dim3(64), dim3(256), 0, stream,
                     hseq + (size_t)256 * BQ * HSZ, Wfcb, bfc, out);
}